// Round 2
// baseline (65.912 us; speedup 1.0000x reference)
//
#include <hip/hip_runtime.h>

// 4-bit comparator over float-encoded bits (values exactly 0.0 or 1.0).
// A,B: [N,4] float32 (MSB first). Outputs: gt [N], eq [N], concatenated in d_out.
// Memory-bound streaming: 32 B in + 8 B out per row.
// 2 rows/thread -> float2 stores; grid-stride with capped grid.

__device__ __forceinline__ void cmp4(const float4 a, const float4 b,
                                     float& gtr, float& eqr)
{
    float a3 = a.x, a2 = a.y, a1 = a.z, a0 = a.w;
    float b3 = b.x, b2 = b.y, b1 = b.z, b0 = b.w;

    // eq_k = NOT(XOR(a,b)) = 1 - (a + b - 2ab); exact on {0,1}
    float eq3 = 1.0f - (a3 + b3 - 2.0f * a3 * b3);
    float eq2 = 1.0f - (a2 + b2 - 2.0f * a2 * b2);
    float eq1 = 1.0f - (a1 + b1 - 2.0f * a1 * b1);
    float eq0 = 1.0f - (a0 + b0 - 2.0f * a0 * b0);

    // gt_k = a AND NOT b
    float gt3 = a3 * (1.0f - b3);
    float gt2 = a2 * (1.0f - b2);
    float gt1 = a1 * (1.0f - b1);
    float gt0 = a0 * (1.0f - b0);

    float eq32  = eq3 * eq2;
    float eq321 = eq32 * eq1;

    float term2 = eq3 * gt2;
    float term3 = eq32 * gt1;
    float term4 = eq321 * gt0;

    // OR(a,b) = a + b - ab
    float t12    = gt3 + term2 - gt3 * term2;
    float t123   = t12 + term3 - t12 * term3;
    gtr          = t123 + term4 - t123 * term4;
    eqr          = eq321 * eq0;
}

__global__ __launch_bounds__(256) void cmp4_kernel(
    const float4* __restrict__ A, const float4* __restrict__ B,
    float2* __restrict__ out_gt, float2* __restrict__ out_eq, int npairs)
{
    int stride = gridDim.x * blockDim.x;
    for (int p = blockIdx.x * blockDim.x + threadIdx.x; p < npairs; p += stride) {
        float4 a0 = A[2 * p];
        float4 a1 = A[2 * p + 1];
        float4 b0 = B[2 * p];
        float4 b1 = B[2 * p + 1];

        float g0, e0, g1, e1;
        cmp4(a0, b0, g0, e0);
        cmp4(a1, b1, g1, e1);

        out_gt[p] = make_float2(g0, g1);
        out_eq[p] = make_float2(e0, e1);
    }
}

// Tail kernel for odd N (not hit for N=8388608, kept for generality).
__global__ void cmp4_tail(const float4* __restrict__ A, const float4* __restrict__ B,
                          float* __restrict__ out_gt, float* __restrict__ out_eq, int row)
{
    float g, e;
    cmp4(A[row], B[row], g, e);
    out_gt[row] = g;
    out_eq[row] = e;
}

extern "C" void kernel_launch(void* const* d_in, const int* in_sizes, int n_in,
                              void* d_out, int out_size, void* d_ws, size_t ws_size,
                              hipStream_t stream)
{
    const float4* A = (const float4*)d_in[0];
    const float4* B = (const float4*)d_in[1];
    int n = in_sizes[0] / 4;             // rows
    float* out = (float*)d_out;
    float* out_gt = out;                 // first output [N]
    float* out_eq = out + n;             // second output [N]

    int npairs = n / 2;
    int block = 256;
    int grid = (npairs + block - 1) / block;
    if (grid > 2048) grid = 2048;        // grid-stride the rest
    cmp4_kernel<<<grid, block, 0, stream>>>(A, B, (float2*)out_gt, (float2*)out_eq, npairs);
    if (n & 1) {
        cmp4_tail<<<1, 1, 0, stream>>>(A, B, out_gt, out_eq, n - 1);
    }
}

// Round 3
// 51.937 us; speedup vs baseline: 1.2691x; 1.2691x over previous
//
#include <hip/hip_runtime.h>

// 4-bit comparator over float-encoded bits (values exactly 0.0 or 1.0).
// A,B: [N,4] float32 (MSB first). Outputs: gt [N], eq [N], concatenated in d_out.
// Memory-bound streaming: 32 B in + 8 B out per row.
// 2 rows/thread BLOCK-STRIDED (all accesses unit-stride across lanes),
// exact-fit grid, non-temporal stores (output is never re-read).

__device__ __forceinline__ void cmp4(const float4 a, const float4 b,
                                     float& gtr, float& eqr)
{
    float a3 = a.x, a2 = a.y, a1 = a.z, a0 = a.w;
    float b3 = b.x, b2 = b.y, b1 = b.z, b0 = b.w;

    // eq_k = NOT(XOR(a,b)) = 1 - (a + b - 2ab); exact on {0,1}
    float eq3 = 1.0f - (a3 + b3 - 2.0f * a3 * b3);
    float eq2 = 1.0f - (a2 + b2 - 2.0f * a2 * b2);
    float eq1 = 1.0f - (a1 + b1 - 2.0f * a1 * b1);
    float eq0 = 1.0f - (a0 + b0 - 2.0f * a0 * b0);

    // gt_k = a AND NOT b
    float gt3 = a3 * (1.0f - b3);
    float gt2 = a2 * (1.0f - b2);
    float gt1 = a1 * (1.0f - b1);
    float gt0 = a0 * (1.0f - b0);

    float eq32  = eq3 * eq2;
    float eq321 = eq32 * eq1;

    float term2 = eq3 * gt2;
    float term3 = eq32 * gt1;
    float term4 = eq321 * gt0;

    // OR(a,b) = a + b - ab
    float t12    = gt3 + term2 - gt3 * term2;
    float t123   = t12 + term3 - t12 * term3;
    gtr          = t123 + term4 - t123 * term4;
    eqr          = eq321 * eq0;
}

__global__ __launch_bounds__(256) void cmp4_kernel(
    const float4* __restrict__ A, const float4* __restrict__ B,
    float* __restrict__ out_gt, float* __restrict__ out_eq, int n)
{
    // Each block owns 2*blockDim consecutive rows; thread handles rows
    // base+tid and base+tid+blockDim -> every access unit-stride across lanes.
    int base = blockIdx.x * (blockDim.x * 2);
    int r0 = base + threadIdx.x;
    int r1 = r0 + blockDim.x;

    if (r1 < n) {
        float4 a0 = A[r0], b0 = B[r0];
        float4 a1 = A[r1], b1 = B[r1];
        float g0, e0, g1, e1;
        cmp4(a0, b0, g0, e0);
        cmp4(a1, b1, g1, e1);
        __builtin_nontemporal_store(g0, &out_gt[r0]);
        __builtin_nontemporal_store(g1, &out_gt[r1]);
        __builtin_nontemporal_store(e0, &out_eq[r0]);
        __builtin_nontemporal_store(e1, &out_eq[r1]);
    } else if (r0 < n) {
        float g0, e0;
        cmp4(A[r0], B[r0], g0, e0);
        __builtin_nontemporal_store(g0, &out_gt[r0]);
        __builtin_nontemporal_store(e0, &out_eq[r0]);
    }
}

extern "C" void kernel_launch(void* const* d_in, const int* in_sizes, int n_in,
                              void* d_out, int out_size, void* d_ws, size_t ws_size,
                              hipStream_t stream)
{
    const float4* A = (const float4*)d_in[0];
    const float4* B = (const float4*)d_in[1];
    int n = in_sizes[0] / 4;             // rows
    float* out = (float*)d_out;
    float* out_gt = out;                 // first output [N]
    float* out_eq = out + n;             // second output [N]

    int block = 256;
    int rows_per_block = block * 2;
    int grid = (n + rows_per_block - 1) / rows_per_block;
    cmp4_kernel<<<grid, block, 0, stream>>>(A, B, out_gt, out_eq, n);
}